// Round 16
// baseline (120.008 us; speedup 1.0000x reference)
//
#include <hip/hip_runtime.h>
#include <hip/hip_bf16.h>
#include <math.h>

#define BATCH 4096
#define XD    784
#define HDIM  512
#define ZD    16
#define NS    8
#define ZS    128
#define NSAMP (BATCH * NS)   // 32768
#define STDN  (ZD * NS * NS) // 1024
#define KP1   800            // K of enc1, padded 784->800
#define NMS   1152           // 128 (mu) + 1024 (std1)
#define NP2   800            // w2t rows padded 784->800 (5*160)

typedef __attribute__((ext_vector_type(8))) short bf16x8;
typedef __attribute__((ext_vector_type(4))) float f32x4;

__device__ inline unsigned short f2bf(float f) {
    unsigned int u = __float_as_uint(f);
    unsigned int r = (u + 0x7fffu + ((u >> 16) & 1u)) >> 16;
    return (unsigned short)r;
}

// HBM -> LDS direct 16B async copy (global_load_lds_dwordx4).
__device__ __forceinline__ void gload16(const unsigned short* g, unsigned short* l) {
    __builtin_amdgcn_global_load_lds(
        (const __attribute__((address_space(1))) unsigned int*)g,
        (__attribute__((address_space(3))) unsigned int*)l,
        16, 0, 0);
}

// ---------------------------------------------------------------------------
// Merged prep (unchanged): W1^T, xpad, [Wmu|Wstd]^T, Wd2^T(row-padded)
// ---------------------------------------------------------------------------
__global__ __launch_bounds__(256)
void prep_kernel(const float* __restrict__ W1, const float* __restrict__ x,
                 const float* __restrict__ Wmu, const float* __restrict__ Wstd,
                 const float* __restrict__ Wd2,
                 unsigned short* __restrict__ w1t, unsigned short* __restrict__ x_bf,
                 unsigned short* __restrict__ wmst, unsigned short* __restrict__ w2tp)
{
    __shared__ unsigned short t[16][17];
    const int tid = threadIdx.x;
    const int tx = tid & 15, ty = tid >> 4;
    const int bid = blockIdx.x;

    if (bid < 1600) {                      // W1^T (K=784 -> 800, N=512)
        const int bx = bid & 31, by = bid >> 5;
        const int n = bx * 16 + tx, k = by * 16 + ty;
        t[ty][tx] = (k < XD) ? f2bf(W1[(size_t)k * HDIM + n]) : (unsigned short)0;
        __syncthreads();
        w1t[(size_t)(bx * 16 + ty) * KP1 + (by * 16 + tx)] = t[tx][ty];
    } else if (bid < 3200) {               // xpad
        const int idx = (bid - 1600) * 256 + tid;
        const int row = idx / 100;
        const int c8 = idx - row * 100;
        const int k0 = c8 * 8;
        ushort4 o0 = {0, 0, 0, 0}, o1 = {0, 0, 0, 0};
        if (k0 < XD) {
            const float4 a = *reinterpret_cast<const float4*>(&x[(size_t)row * XD + k0]);
            const float4 b = *reinterpret_cast<const float4*>(&x[(size_t)row * XD + k0 + 4]);
            o0.x = f2bf(a.x); o0.y = f2bf(a.y); o0.z = f2bf(a.z); o0.w = f2bf(a.w);
            o1.x = f2bf(b.x); o1.y = f2bf(b.y); o1.z = f2bf(b.z); o1.w = f2bf(b.w);
        }
        *reinterpret_cast<ushort4*>(&x_bf[(size_t)row * KP1 + k0]) = o0;
        *reinterpret_cast<ushort4*>(&x_bf[(size_t)row * KP1 + k0 + 4]) = o1;
    } else if (bid < 5504) {               // [Wmu|Wstd]^T (N=1152, K=512)
        const int b = bid - 3200;
        const int bx = b % 72, by = b / 72;
        const int n = bx * 16 + tx, k = by * 16 + ty;
        const float v = (n < ZS) ? Wmu[(size_t)k * ZS + n]
                                 : Wstd[(size_t)k * STDN + (n - ZS)];
        t[ty][tx] = f2bf(v);
        __syncthreads();
        wmst[(size_t)(bx * 16 + ty) * HDIM + (by * 16 + tx)] = t[tx][ty];
    } else {                               // Wd2^T (N=784 -> 800+ rows, K=512)
        const int b = bid - 5504;
        const int bx = b % 50, by = b / 50;
        const int n = bx * 16 + tx, k = by * 16 + ty;
        t[ty][tx] = (n < XD) ? f2bf(Wd2[(size_t)k * XD + n]) : (unsigned short)0;
        __syncthreads();
        w2tp[(size_t)(bx * 16 + ty) * HDIM + (by * 16 + tx)] = t[tx][ty];
    }
}

// ---------------------------------------------------------------------------
// Encoder MFMA GEMM (unchanged from R15): XCD-swizzled, NF=8 body.
// ---------------------------------------------------------------------------
#define EEBLD 132

template<int OUT_BF16>
__global__ __launch_bounds__(256)
void enc_mfma(const unsigned short* __restrict__ A,
              const unsigned short* __restrict__ Bt,
              const float* __restrict__ bias0, const float* __restrict__ bias1,
              int bsplit, void* __restrict__ Cout, int ldc, int K, int NT)
{
    __shared__ __align__(16) char smem[64 * EEBLD * 4];
    unsigned short* Alb = (unsigned short*)smem;
    unsigned short* Blb = (unsigned short*)(smem + 16384);
    float* eb = (float*)smem;

    const int tid = threadIdx.x;
    const int bid = blockIdx.x;
    const int cxd = bid & 7;
    const int s = bid >> 3;
    const int m0 = (cxd * 4 + s / NT) * 128;
    const int n0 = (s % NT) * 128;
    const int wave = tid >> 6;
    const int lane = tid & 63;
    const int lr = lane & 15;
    const int kg = lane >> 4;
    const int nkt = K >> 5;

    const int rS = tid >> 2;
    const int cS = (tid & 3) * 8;

    f32x4 acc[2][8];
    #pragma unroll
    for (int i = 0; i < 2; ++i)
        #pragma unroll
        for (int j = 0; j < 8; ++j)
            acc[i][j] = (f32x4){0.f, 0.f, 0.f, 0.f};

    #define ENC_STAGE(b, kt)                                                          \
    {                                                                                 \
        const int k0 = (kt) * 32 + cS;                                                \
        gload16(&A[(size_t)(m0 + rS) * K + k0],       &Alb[(b) * 4096 + tid * 8]);    \
        gload16(&A[(size_t)(m0 + rS + 64) * K + k0],  &Alb[(b) * 4096 + (tid + 256) * 8]); \
        gload16(&Bt[(size_t)(n0 + rS) * K + k0],      &Blb[(b) * 4096 + tid * 8]);    \
        gload16(&Bt[(size_t)(n0 + rS + 64) * K + k0], &Blb[(b) * 4096 + (tid + 256) * 8]); \
    }

    ENC_STAGE(0, 0);
    __syncthreads();

    int buf = 0;
    for (int kt = 0; kt < nkt; ++kt) {
        if (kt + 1 < nkt) ENC_STAGE(buf ^ 1, kt + 1);

        bf16x8 af[2], bfr[8];
        #pragma unroll
        for (int mi = 0; mi < 2; ++mi)
            af[mi] = *reinterpret_cast<const bf16x8*>(
                &Alb[buf * 4096 + (wave * 32 + mi * 16 + lr) * 32 + kg * 8]);
        #pragma unroll
        for (int nf = 0; nf < 8; ++nf)
            bfr[nf] = *reinterpret_cast<const bf16x8*>(
                &Blb[buf * 4096 + (nf * 16 + lr) * 32 + kg * 8]);
        #pragma unroll
        for (int mi = 0; mi < 2; ++mi)
            #pragma unroll
            for (int nf = 0; nf < 8; ++nf)
                acc[mi][nf] = __builtin_amdgcn_mfma_f32_16x16x32_bf16(af[mi], bfr[nf], acc[mi][nf], 0, 0, 0);

        __syncthreads();
        buf ^= 1;
    }

    #pragma unroll
    for (int mi = 0; mi < 2; ++mi) {
        __syncthreads();
        #pragma unroll
        for (int nf = 0; nf < 8; ++nf) {
            const int ci = nf * 16 + lr;
            const int col = n0 + ci;
            const float bb = (col < bsplit) ? bias0[col] : bias1[col - bsplit];
            #pragma unroll
            for (int j = 0; j < 4; ++j) {
                const int ri = wave * 16 + kg * 4 + j;
                float v = acc[mi][nf][j] + bb;
                if (OUT_BF16) v = fmaxf(v, 0.f);
                eb[ri * EEBLD + ci] = v;
            }
        }
        __syncthreads();
        #pragma unroll
        for (int e = 0; e < 8; ++e) {
            const int q = e * 256 + tid;
            const int ri = q >> 5;
            const int c4 = (q & 31) * 4;
            const int grow = m0 + (ri >> 4) * 32 + mi * 16 + (ri & 15);
            const float4 v = *reinterpret_cast<const float4*>(&eb[ri * EEBLD + c4]);
            if (OUT_BF16) {
                ushort4 o;
                o.x = f2bf(v.x); o.y = f2bf(v.y); o.z = f2bf(v.z); o.w = f2bf(v.w);
                *reinterpret_cast<ushort4*>(
                    &((unsigned short*)Cout)[(size_t)grow * ldc + n0 + c4]) = o;
            } else {
                *reinterpret_cast<float4*>(
                    &((float*)Cout)[(size_t)grow * ldc + n0 + c4]) = v;
            }
        }
    }
    #undef ENC_STAGE
}

// ---------------------------------------------------------------------------
// Fused sample + hd (unchanged).
// ---------------------------------------------------------------------------
__global__ __launch_bounds__(256)
void samphd_kernel(const float* __restrict__ ms, const float* __restrict__ eps,
                   const float* __restrict__ Wd1, const float* __restrict__ bd1,
                   float* __restrict__ mu_out, float* __restrict__ z_out,
                   float* __restrict__ logvar_out, unsigned short* __restrict__ hd)
{
    __shared__ float zsh[16][16];
    const int tid = threadIdx.x;
    const int b0 = blockIdx.x * 2;
    const int b = b0 + (tid >> 7);
    const int r = tid & 127;
    const int d = r & 15;
    const int s1 = r >> 4;

    {
        const float* v = &ms[(size_t)b * NMS + ZS + r * NS];
        const float* e = &eps[(size_t)b * ZS + d];
        float zacc = 0.f, dacc = 0.f;
        #pragma unroll
        for (int k = 0; k < NS; ++k) {
            const float vv = v[k];
            zacc += vv * e[16 * k];
            dacc += vv * vv;
        }
        const float muv = ms[(size_t)b * NMS + r];
        mu_out[(size_t)b * ZS + r] = muv;
        const float zv = muv + zacc;
        const size_t orow = (size_t)(b * NS + s1) * ZD + d;
        z_out[orow] = zv;
        logvar_out[orow] = logf(dacc);
        zsh[(tid >> 7) * 8 + s1][d] = zv;
    }
    __syncthreads();

    for (int e2 = 0; e2 < 8; ++e2) {
        const int q = e2 * 256 + tid;
        const int zr = q >> 7;
        const int n0 = (q & 127) * 4;
        float4 a = *reinterpret_cast<const float4*>(&bd1[n0]);
        #pragma unroll
        for (int k = 0; k < ZD; ++k) {
            const float zk = zsh[zr][k];
            const float4 w = *reinterpret_cast<const float4*>(&Wd1[(size_t)k * HDIM + n0]);
            a.x += zk * w.x; a.y += zk * w.y; a.z += zk * w.z; a.w += zk * w.w;
        }
        ushort4 o;
        o.x = f2bf(fmaxf(a.x, 0.f));
        o.y = f2bf(fmaxf(a.y, 0.f));
        o.z = f2bf(fmaxf(a.z, 0.f));
        o.w = f2bf(fmaxf(a.w, 0.f));
        *reinterpret_cast<ushort4*>(&hd[(size_t)(b0 * 8 + zr) * HDIM + n0]) = o;
    }
}

// ---------------------------------------------------------------------------
// Decoder GEMM: R13 loop body, tail-packed tiling.
// BM=64, BN=160: LDS = 2*(4KB A + 12KB B) = 32KB -> 5 blocks/CU ->
// capacity 1280; grid 512 m-tiles x 5 chunks = 2560 = EXACTLY 2 rounds
// (was 1280 blocks vs 1024 capacity = 1.25 -> 2 rounds with 80%-idle tail).
// Staging: 4 uniform gloads/thread (1 A + 3 B), vmcnt(4) counted pipeline.
// XCD swizzle: cxd owns 64 contiguous m-tiles; 5 chunks/m-tile adjacent.
// ---------------------------------------------------------------------------
#define DBM 64
#define DBN 160
#define DNKT 16
#define DEBLD 164

__global__ __launch_bounds__(256)
void decoder_mfma(const unsigned short* __restrict__ hd,
                  const unsigned short* __restrict__ w2tp,
                  const float* __restrict__ bd2,
                  float* __restrict__ recon)
{
    __shared__ __align__(16) char smem[32768];
    unsigned short* Alb = (unsigned short*)smem;            // [2][64*32]  (4KB each)
    unsigned short* Blb = (unsigned short*)(smem + 8192);   // [2][192*32] (12KB each)
    float* eb = (float*)smem;                               // [32][164] aliased

    const int tid = threadIdx.x;
    // XCD-aware swizzle: 2560 blocks = 8 XCDs x 64 m-tiles x 5 n-chunks
    const int bid = blockIdx.x;
    const int cxd = bid & 7;
    const int s = bid >> 3;                 // 0..319
    const int m0 = (cxd * 64 + s / 5) * DBM;
    const int n0 = (s % 5) * DBN;

    const int wave = tid >> 6;
    const int wr = wave >> 1;               // rows wr*32
    const int wc = wave & 1;                // cols wc*80
    const int lane = tid & 63;
    const int lr = lane & 15;
    const int kg = lane >> 4;

    const int rS = tid >> 2;                // 0..63
    const int cS = (tid & 3) * 8;

    f32x4 acc[2][5];
    #pragma unroll
    for (int i = 0; i < 2; ++i)
        #pragma unroll
        for (int j = 0; j < 5; ++j)
            acc[i][j] = (f32x4){0.f, 0.f, 0.f, 0.f};

    // 4 uniform gloads/thread: A 64x32 (1) + B 192x32 (3)
    #define DEC_STAGE(b, kt)                                                             \
    {                                                                                    \
        const int k0 = (kt) * 32 + cS;                                                   \
        gload16(&hd[(size_t)(m0 + rS) * HDIM + k0],          &Alb[(b) * 2048 + tid * 8]); \
        gload16(&w2tp[(size_t)(n0 + rS) * HDIM + k0],        &Blb[(b) * 6144 + tid * 8]); \
        gload16(&w2tp[(size_t)(n0 + rS + 64) * HDIM + k0],   &Blb[(b) * 6144 + (tid + 256) * 8]); \
        gload16(&w2tp[(size_t)(n0 + rS + 128) * HDIM + k0],  &Blb[(b) * 6144 + (tid + 512) * 8]); \
    }

    DEC_STAGE(0, 0);

    int buf = 0;
    for (int kt = 0; kt < DNKT; ++kt) {
        if (kt + 1 < DNKT) {
            DEC_STAGE(buf ^ 1, kt + 1);
            asm volatile("s_waitcnt vmcnt(4)" ::: "memory");
        } else {
            asm volatile("s_waitcnt vmcnt(0)" ::: "memory");
        }
        __builtin_amdgcn_s_barrier();
        __builtin_amdgcn_sched_barrier(0);

        bf16x8 af[2], bfr[5];
        #pragma unroll
        for (int mi = 0; mi < 2; ++mi)
            af[mi] = *reinterpret_cast<const bf16x8*>(
                &Alb[buf * 2048 + (wr * 32 + mi * 16 + lr) * 32 + kg * 8]);
        #pragma unroll
        for (int nf = 0; nf < 5; ++nf)
            bfr[nf] = *reinterpret_cast<const bf16x8*>(
                &Blb[buf * 6144 + (wc * 80 + nf * 16 + lr) * 32 + kg * 8]);
        #pragma unroll
        for (int mi = 0; mi < 2; ++mi)
            #pragma unroll
            for (int nf = 0; nf < 5; ++nf)
                acc[mi][nf] = __builtin_amdgcn_mfma_f32_16x16x32_bf16(af[mi], bfr[nf], acc[mi][nf], 0, 0, 0);

        __builtin_amdgcn_sched_barrier(0);
        __builtin_amdgcn_s_barrier();
        buf ^= 1;
    }

    // ---- LDS-staged coalesced epilogue, nontemporal ext-vector stores
    #pragma unroll
    for (int mi = 0; mi < 2; ++mi) {
        __syncthreads();
        #pragma unroll
        for (int nf = 0; nf < 5; ++nf) {
            const int ci = wc * 80 + nf * 16 + lr;
            const int col = n0 + ci;
            const float bb = (col < XD) ? bd2[col] : 0.f;
            #pragma unroll
            for (int j = 0; j < 4; ++j) {
                const int ri = wr * 16 + kg * 4 + j;
                const float v = acc[mi][nf][j] + bb;
                eb[ri * DEBLD + ci] = __builtin_amdgcn_rcpf(1.f + __expf(-v));
            }
        }
        __syncthreads();
        #pragma unroll
        for (int e = 0; e < 5; ++e) {
            const int q = e * 256 + tid;
            const int ri = q / 40;              // 0..31
            const int c4 = (q - ri * 40) * 4;   // 0..156
            const int col = n0 + c4;
            if (col < XD) {
                const int grow = m0 + (ri >> 4) * 32 + mi * 16 + (ri & 15);
                const f32x4 v = *reinterpret_cast<const f32x4*>(&eb[ri * DEBLD + c4]);
                __builtin_nontemporal_store(
                    v, reinterpret_cast<f32x4*>(&recon[(size_t)grow * XD + col]));
            }
        }
    }
    #undef DEC_STAGE
}

// ---------------------------------------------------------------------------
extern "C" void kernel_launch(void* const* d_in, const int* in_sizes, int n_in,
                              void* d_out, int out_size, void* d_ws, size_t ws_size,
                              hipStream_t stream)
{
    const float* x    = (const float*)d_in[0];
    const float* eps  = (const float*)d_in[1];
    const float* W1   = (const float*)d_in[2];
    const float* b1   = (const float*)d_in[3];
    const float* Wmu  = (const float*)d_in[4];
    const float* bmu  = (const float*)d_in[5];
    const float* Wstd = (const float*)d_in[6];
    const float* bstd = (const float*)d_in[7];
    const float* Wd1  = (const float*)d_in[8];
    const float* bd1  = (const float*)d_in[9];
    const float* Wd2  = (const float*)d_in[10];
    const float* bd2  = (const float*)d_in[11];

    float* out    = (float*)d_out;
    float* recon  = out;
    float* mu     = recon + (size_t)NSAMP * XD;
    float* logvar = mu + (size_t)BATCH * ZS;
    float* zout   = logvar + (size_t)NSAMP * ZD;

    char* wsb = (char*)d_ws;
    unsigned short* hd   = (unsigned short*)wsb;                            // 32 MiB
    unsigned short* x_bf = (unsigned short*)wsb;                            // 6.25 MiB
    unsigned short* h    = (unsigned short*)(wsb + (size_t)68 * 1048576 / 10);
    float*          ms   = (float*)(wsb + (size_t)11 * 1048576);
    unsigned short* w1t  = (unsigned short*)(wsb + (size_t)295 * 1048576 / 10);
    unsigned short* wmst = (unsigned short*)(wsb + (size_t)305 * 1048576 / 10);
    unsigned short* w2tp = (unsigned short*)(wsb + (size_t)32 * 1048576);   // 832x512 bf16 reachable

    prep_kernel<<<7104, 256, 0, stream>>>(W1, x, Wmu, Wstd, Wd2, w1t, x_bf, wmst, w2tp);

    // enc1: grid 32x4 = 128 blocks, XCD-swizzled (NT=4)
    enc_mfma<1><<<128, 256, 0, stream>>>(
        x_bf, w1t, b1, b1, HDIM, h, HDIM, KP1, 4);
    // enc2: grid 32x9 = 288 blocks, XCD-swizzled (NT=9)
    enc_mfma<0><<<288, 256, 0, stream>>>(
        h, wmst, bmu, bstd, ZS, ms, NMS, HDIM, 9);

    samphd_kernel<<<BATCH / 2, 256, 0, stream>>>(ms, eps, Wd1, bd1, mu, zout, logvar, hd);

    // tail-packed decoder: 2560 blocks = exactly 2 rounds at 5 blocks/CU
    decoder_mfma<<<2560, 256, 0, stream>>>(hd, w2tp, bd2, recon);
}

// Round 17
// 103.227 us; speedup vs baseline: 1.1626x; 1.1626x over previous
//
#include <hip/hip_runtime.h>
#include <hip/hip_bf16.h>
#include <math.h>

#define BATCH 4096
#define XD    784
#define HDIM  512
#define ZD    16
#define NS    8
#define ZS    128
#define NSAMP (BATCH * NS)   // 32768
#define STDN  (ZD * NS * NS) // 1024
#define KP1   800            // K of enc1, padded 784->800
#define NMS   1152           // 128 (mu) + 1024 (std1)
#define NP2   800            // w2t rows padded 784->800 (5*160)

typedef __attribute__((ext_vector_type(8))) short bf16x8;
typedef __attribute__((ext_vector_type(4))) float f32x4;

__device__ inline unsigned short f2bf(float f) {
    unsigned int u = __float_as_uint(f);
    unsigned int r = (u + 0x7fffu + ((u >> 16) & 1u)) >> 16;
    return (unsigned short)r;
}

// HBM -> LDS direct 16B async copy (global_load_lds_dwordx4).
__device__ __forceinline__ void gload16(const unsigned short* g, unsigned short* l) {
    __builtin_amdgcn_global_load_lds(
        (const __attribute__((address_space(1))) unsigned int*)g,
        (__attribute__((address_space(3))) unsigned int*)l,
        16, 0, 0);
}

// ---------------------------------------------------------------------------
// Merged prep (unchanged): W1^T, xpad, [Wmu|Wstd]^T, Wd2^T(row-padded)
// ---------------------------------------------------------------------------
__global__ __launch_bounds__(256)
void prep_kernel(const float* __restrict__ W1, const float* __restrict__ x,
                 const float* __restrict__ Wmu, const float* __restrict__ Wstd,
                 const float* __restrict__ Wd2,
                 unsigned short* __restrict__ w1t, unsigned short* __restrict__ x_bf,
                 unsigned short* __restrict__ wmst, unsigned short* __restrict__ w2tp)
{
    __shared__ unsigned short t[16][17];
    const int tid = threadIdx.x;
    const int tx = tid & 15, ty = tid >> 4;
    const int bid = blockIdx.x;

    if (bid < 1600) {                      // W1^T (K=784 -> 800, N=512)
        const int bx = bid & 31, by = bid >> 5;
        const int n = bx * 16 + tx, k = by * 16 + ty;
        t[ty][tx] = (k < XD) ? f2bf(W1[(size_t)k * HDIM + n]) : (unsigned short)0;
        __syncthreads();
        w1t[(size_t)(bx * 16 + ty) * KP1 + (by * 16 + tx)] = t[tx][ty];
    } else if (bid < 3200) {               // xpad
        const int idx = (bid - 1600) * 256 + tid;
        const int row = idx / 100;
        const int c8 = idx - row * 100;
        const int k0 = c8 * 8;
        ushort4 o0 = {0, 0, 0, 0}, o1 = {0, 0, 0, 0};
        if (k0 < XD) {
            const float4 a = *reinterpret_cast<const float4*>(&x[(size_t)row * XD + k0]);
            const float4 b = *reinterpret_cast<const float4*>(&x[(size_t)row * XD + k0 + 4]);
            o0.x = f2bf(a.x); o0.y = f2bf(a.y); o0.z = f2bf(a.z); o0.w = f2bf(a.w);
            o1.x = f2bf(b.x); o1.y = f2bf(b.y); o1.z = f2bf(b.z); o1.w = f2bf(b.w);
        }
        *reinterpret_cast<ushort4*>(&x_bf[(size_t)row * KP1 + k0]) = o0;
        *reinterpret_cast<ushort4*>(&x_bf[(size_t)row * KP1 + k0 + 4]) = o1;
    } else if (bid < 5504) {               // [Wmu|Wstd]^T (N=1152, K=512)
        const int b = bid - 3200;
        const int bx = b % 72, by = b / 72;
        const int n = bx * 16 + tx, k = by * 16 + ty;
        const float v = (n < ZS) ? Wmu[(size_t)k * ZS + n]
                                 : Wstd[(size_t)k * STDN + (n - ZS)];
        t[ty][tx] = f2bf(v);
        __syncthreads();
        wmst[(size_t)(bx * 16 + ty) * HDIM + (by * 16 + tx)] = t[tx][ty];
    } else {                               // Wd2^T (N=784 -> 800+ rows, K=512)
        const int b = bid - 5504;
        const int bx = b % 50, by = b / 50;
        const int n = bx * 16 + tx, k = by * 16 + ty;
        t[ty][tx] = (n < XD) ? f2bf(Wd2[(size_t)k * XD + n]) : (unsigned short)0;
        __syncthreads();
        w2tp[(size_t)(bx * 16 + ty) * HDIM + (by * 16 + tx)] = t[tx][ty];
    }
}

// ---------------------------------------------------------------------------
// enc1: BM=64, BN=128, K=800 -> grid 256 (full machine; was 128 blocks).
// Waves 2x2 (each 32x64, acc[2][4]); 3 uniform gloads/thread; XCD swizzle.
// ---------------------------------------------------------------------------
#define EEBLD 132

__global__ __launch_bounds__(256)
void enc1_mfma(const unsigned short* __restrict__ A,
               const unsigned short* __restrict__ Bt,
               const float* __restrict__ bias, unsigned short* __restrict__ Cout)
{
    __shared__ __align__(16) char smem[64 * EEBLD * 4];   // eb 33.8KB > staging 24KB
    unsigned short* Alb = (unsigned short*)smem;            // [2][64*32]  (4KB each)
    unsigned short* Blb = (unsigned short*)(smem + 8192);   // [2][128*32] (8KB each)
    float* eb = (float*)smem;

    const int tid = threadIdx.x;
    // XCD swizzle: 256 blocks = 8 XCDs x 8 m-tiles x 4 n-chunks
    const int bid = blockIdx.x;
    const int cxd = bid & 7;
    const int s = bid >> 3;                  // 0..31
    const int m0 = (cxd * 8 + s / 4) * 64;
    const int n0 = (s % 4) * 128;

    const int wave = tid >> 6;
    const int wr = wave >> 1;                // rows wr*32
    const int wc = wave & 1;                 // cols wc*64
    const int lane = tid & 63;
    const int lr = lane & 15;
    const int kg = lane >> 4;
    const int nkt = KP1 >> 5;                // 25

    const int rS = tid >> 2;                 // 0..63
    const int cS = (tid & 3) * 8;

    f32x4 acc[2][4];
    #pragma unroll
    for (int i = 0; i < 2; ++i)
        #pragma unroll
        for (int j = 0; j < 4; ++j)
            acc[i][j] = (f32x4){0.f, 0.f, 0.f, 0.f};

    #define E1_STAGE(b, kt)                                                           \
    {                                                                                 \
        const int k0 = (kt) * 32 + cS;                                                \
        gload16(&A[(size_t)(m0 + rS) * KP1 + k0],       &Alb[(b) * 2048 + tid * 8]);  \
        gload16(&Bt[(size_t)(n0 + rS) * KP1 + k0],      &Blb[(b) * 4096 + tid * 8]);  \
        gload16(&Bt[(size_t)(n0 + rS + 64) * KP1 + k0], &Blb[(b) * 4096 + (tid + 256) * 8]); \
    }

    E1_STAGE(0, 0);
    __syncthreads();

    int buf = 0;
    for (int kt = 0; kt < nkt; ++kt) {
        if (kt + 1 < nkt) E1_STAGE(buf ^ 1, kt + 1);

        bf16x8 af[2], bfr[4];
        #pragma unroll
        for (int mi = 0; mi < 2; ++mi)
            af[mi] = *reinterpret_cast<const bf16x8*>(
                &Alb[buf * 2048 + (wr * 32 + mi * 16 + lr) * 32 + kg * 8]);
        #pragma unroll
        for (int nf = 0; nf < 4; ++nf)
            bfr[nf] = *reinterpret_cast<const bf16x8*>(
                &Blb[buf * 4096 + (wc * 64 + nf * 16 + lr) * 32 + kg * 8]);
        #pragma unroll
        for (int mi = 0; mi < 2; ++mi)
            #pragma unroll
            for (int nf = 0; nf < 4; ++nf)
                acc[mi][nf] = __builtin_amdgcn_mfma_f32_16x16x32_bf16(af[mi], bfr[nf], acc[mi][nf], 0, 0, 0);

        __syncthreads();
        buf ^= 1;
    }

    // coalesced epilogue: 64x128 tile in one pass
    #pragma unroll
    for (int nf = 0; nf < 4; ++nf) {
        const int ci = wc * 64 + nf * 16 + lr;
        const float bb = bias[n0 + ci];
        #pragma unroll
        for (int mi = 0; mi < 2; ++mi)
            #pragma unroll
            for (int j = 0; j < 4; ++j) {
                const int ri = wr * 32 + mi * 16 + kg * 4 + j;
                eb[ri * EEBLD + ci] = fmaxf(acc[mi][nf][j] + bb, 0.f);
            }
    }
    __syncthreads();
    #pragma unroll
    for (int e = 0; e < 8; ++e) {
        const int q = e * 256 + tid;        // 0..2047
        const int ri = q >> 5;              // 0..63
        const int c4 = (q & 31) * 4;        // 0..124
        const float4 v = *reinterpret_cast<const float4*>(&eb[ri * EEBLD + c4]);
        ushort4 o;
        o.x = f2bf(v.x); o.y = f2bf(v.y); o.z = f2bf(v.z); o.w = f2bf(v.w);
        *reinterpret_cast<ushort4*>(&Cout[(size_t)(m0 + ri) * HDIM + n0 + c4]) = o;
    }
    #undef E1_STAGE
}

// ---------------------------------------------------------------------------
// enc2 (unchanged proven template): XCD-swizzled, NF=8 body.
// ---------------------------------------------------------------------------
template<int OUT_BF16>
__global__ __launch_bounds__(256)
void enc_mfma(const unsigned short* __restrict__ A,
              const unsigned short* __restrict__ Bt,
              const float* __restrict__ bias0, const float* __restrict__ bias1,
              int bsplit, void* __restrict__ Cout, int ldc, int K, int NT)
{
    __shared__ __align__(16) char smem[64 * EEBLD * 4];
    unsigned short* Alb = (unsigned short*)smem;
    unsigned short* Blb = (unsigned short*)(smem + 16384);
    float* eb = (float*)smem;

    const int tid = threadIdx.x;
    const int bid = blockIdx.x;
    const int cxd = bid & 7;
    const int s = bid >> 3;
    const int m0 = (cxd * 4 + s / NT) * 128;
    const int n0 = (s % NT) * 128;
    const int wave = tid >> 6;
    const int lane = tid & 63;
    const int lr = lane & 15;
    const int kg = lane >> 4;
    const int nkt = K >> 5;

    const int rS = tid >> 2;
    const int cS = (tid & 3) * 8;

    f32x4 acc[2][8];
    #pragma unroll
    for (int i = 0; i < 2; ++i)
        #pragma unroll
        for (int j = 0; j < 8; ++j)
            acc[i][j] = (f32x4){0.f, 0.f, 0.f, 0.f};

    #define ENC_STAGE(b, kt)                                                          \
    {                                                                                 \
        const int k0 = (kt) * 32 + cS;                                                \
        gload16(&A[(size_t)(m0 + rS) * K + k0],       &Alb[(b) * 4096 + tid * 8]);    \
        gload16(&A[(size_t)(m0 + rS + 64) * K + k0],  &Alb[(b) * 4096 + (tid + 256) * 8]); \
        gload16(&Bt[(size_t)(n0 + rS) * K + k0],      &Blb[(b) * 4096 + tid * 8]);    \
        gload16(&Bt[(size_t)(n0 + rS + 64) * K + k0], &Blb[(b) * 4096 + (tid + 256) * 8]); \
    }

    ENC_STAGE(0, 0);
    __syncthreads();

    int buf = 0;
    for (int kt = 0; kt < nkt; ++kt) {
        if (kt + 1 < nkt) ENC_STAGE(buf ^ 1, kt + 1);

        bf16x8 af[2], bfr[8];
        #pragma unroll
        for (int mi = 0; mi < 2; ++mi)
            af[mi] = *reinterpret_cast<const bf16x8*>(
                &Alb[buf * 4096 + (wave * 32 + mi * 16 + lr) * 32 + kg * 8]);
        #pragma unroll
        for (int nf = 0; nf < 8; ++nf)
            bfr[nf] = *reinterpret_cast<const bf16x8*>(
                &Blb[buf * 4096 + (nf * 16 + lr) * 32 + kg * 8]);
        #pragma unroll
        for (int mi = 0; mi < 2; ++mi)
            #pragma unroll
            for (int nf = 0; nf < 8; ++nf)
                acc[mi][nf] = __builtin_amdgcn_mfma_f32_16x16x32_bf16(af[mi], bfr[nf], acc[mi][nf], 0, 0, 0);

        __syncthreads();
        buf ^= 1;
    }

    #pragma unroll
    for (int mi = 0; mi < 2; ++mi) {
        __syncthreads();
        #pragma unroll
        for (int nf = 0; nf < 8; ++nf) {
            const int ci = nf * 16 + lr;
            const int col = n0 + ci;
            const float bb = (col < bsplit) ? bias0[col] : bias1[col - bsplit];
            #pragma unroll
            for (int j = 0; j < 4; ++j) {
                const int ri = wave * 16 + kg * 4 + j;
                float v = acc[mi][nf][j] + bb;
                if (OUT_BF16) v = fmaxf(v, 0.f);
                eb[ri * EEBLD + ci] = v;
            }
        }
        __syncthreads();
        #pragma unroll
        for (int e = 0; e < 8; ++e) {
            const int q = e * 256 + tid;
            const int ri = q >> 5;
            const int c4 = (q & 31) * 4;
            const int grow = m0 + (ri >> 4) * 32 + mi * 16 + (ri & 15);
            const float4 v = *reinterpret_cast<const float4*>(&eb[ri * EEBLD + c4]);
            if (OUT_BF16) {
                ushort4 o;
                o.x = f2bf(v.x); o.y = f2bf(v.y); o.z = f2bf(v.z); o.w = f2bf(v.w);
                *reinterpret_cast<ushort4*>(
                    &((unsigned short*)Cout)[(size_t)grow * ldc + n0 + c4]) = o;
            } else {
                *reinterpret_cast<float4*>(
                    &((float*)Cout)[(size_t)grow * ldc + n0 + c4]) = v;
            }
        }
    }
    #undef ENC_STAGE
}

// ---------------------------------------------------------------------------
// Fused sample + hd (unchanged).
// ---------------------------------------------------------------------------
__global__ __launch_bounds__(256)
void samphd_kernel(const float* __restrict__ ms, const float* __restrict__ eps,
                   const float* __restrict__ Wd1, const float* __restrict__ bd1,
                   float* __restrict__ mu_out, float* __restrict__ z_out,
                   float* __restrict__ logvar_out, unsigned short* __restrict__ hd)
{
    __shared__ float zsh[16][16];
    const int tid = threadIdx.x;
    const int b0 = blockIdx.x * 2;
    const int b = b0 + (tid >> 7);
    const int r = tid & 127;
    const int d = r & 15;
    const int s1 = r >> 4;

    {
        const float* v = &ms[(size_t)b * NMS + ZS + r * NS];
        const float* e = &eps[(size_t)b * ZS + d];
        float zacc = 0.f, dacc = 0.f;
        #pragma unroll
        for (int k = 0; k < NS; ++k) {
            const float vv = v[k];
            zacc += vv * e[16 * k];
            dacc += vv * vv;
        }
        const float muv = ms[(size_t)b * NMS + r];
        mu_out[(size_t)b * ZS + r] = muv;
        const float zv = muv + zacc;
        const size_t orow = (size_t)(b * NS + s1) * ZD + d;
        z_out[orow] = zv;
        logvar_out[orow] = logf(dacc);
        zsh[(tid >> 7) * 8 + s1][d] = zv;
    }
    __syncthreads();

    for (int e2 = 0; e2 < 8; ++e2) {
        const int q = e2 * 256 + tid;
        const int zr = q >> 7;
        const int n0 = (q & 127) * 4;
        float4 a = *reinterpret_cast<const float4*>(&bd1[n0]);
        #pragma unroll
        for (int k = 0; k < ZD; ++k) {
            const float zk = zsh[zr][k];
            const float4 w = *reinterpret_cast<const float4*>(&Wd1[(size_t)k * HDIM + n0]);
            a.x += zk * w.x; a.y += zk * w.y; a.z += zk * w.z; a.w += zk * w.w;
        }
        ushort4 o;
        o.x = f2bf(fmaxf(a.x, 0.f));
        o.y = f2bf(fmaxf(a.y, 0.f));
        o.z = f2bf(fmaxf(a.z, 0.f));
        o.w = f2bf(fmaxf(a.w, 0.f));
        *reinterpret_cast<ushort4*>(&hd[(size_t)(b0 * 8 + zr) * HDIM + n0]) = o;
    }
}

// ---------------------------------------------------------------------------
// Decoder GEMM: REVERTED to R13-exact (best measured ~50us).
// BM=128, BN=160, grid 1280, XCD swizzle, vmcnt(5) pipeline,
// coalesced LDS epilogue with nontemporal stores. No setprio.
// ---------------------------------------------------------------------------
#define DBM 128
#define DBN 160
#define DNKT 16
#define DEBLD 164

__global__ __launch_bounds__(256)
void decoder_mfma(const unsigned short* __restrict__ hd,
                  const unsigned short* __restrict__ w2tp,
                  const float* __restrict__ bd2,
                  float* __restrict__ recon)
{
    __shared__ __align__(16) char smem[40960];
    unsigned short* Alb = (unsigned short*)smem;            // [2][128*32]
    unsigned short* Blb = (unsigned short*)(smem + 16384);  // [2][192*32]
    float* eb = (float*)smem;

    const int tid = threadIdx.x;
    // XCD-aware swizzle: 1280 blocks = 8 XCDs x 32 m-tiles x 5 n-chunks
    const int bid = blockIdx.x;
    const int cxd = bid & 7;
    const int s = bid >> 3;
    const int m0 = (cxd * 32 + s / 5) * DBM;
    const int n0 = (s % 5) * DBN;

    const int wave = tid >> 6;
    const int wr = wave >> 1;
    const int wc = wave & 1;
    const int lane = tid & 63;
    const int lr = lane & 15;
    const int kg = lane >> 4;

    const int rS = tid >> 2;
    const int cS = (tid & 3) * 8;

    f32x4 acc[4][5];
    #pragma unroll
    for (int i = 0; i < 4; ++i)
        #pragma unroll
        for (int j = 0; j < 5; ++j)
            acc[i][j] = (f32x4){0.f, 0.f, 0.f, 0.f};

    #define DEC_STAGE(b, kt)                                                             \
    {                                                                                    \
        const int k0 = (kt) * 32 + cS;                                                   \
        gload16(&hd[(size_t)(m0 + rS) * HDIM + k0],          &Alb[(b) * 4096 + tid * 8]); \
        gload16(&hd[(size_t)(m0 + rS + 64) * HDIM + k0],     &Alb[(b) * 4096 + (tid + 256) * 8]); \
        gload16(&w2tp[(size_t)(n0 + rS) * HDIM + k0],        &Blb[(b) * 6144 + tid * 8]); \
        gload16(&w2tp[(size_t)(n0 + rS + 64) * HDIM + k0],   &Blb[(b) * 6144 + (tid + 256) * 8]); \
        gload16(&w2tp[(size_t)(n0 + rS + 128) * HDIM + k0],  &Blb[(b) * 6144 + (tid + 512) * 8]); \
    }

    DEC_STAGE(0, 0);

    int buf = 0;
    for (int kt = 0; kt < DNKT; ++kt) {
        if (kt + 1 < DNKT) {
            DEC_STAGE(buf ^ 1, kt + 1);
            asm volatile("s_waitcnt vmcnt(5)" ::: "memory");
        } else {
            asm volatile("s_waitcnt vmcnt(0)" ::: "memory");
        }
        __builtin_amdgcn_s_barrier();
        __builtin_amdgcn_sched_barrier(0);

        bf16x8 af[4], bfr[5];
        #pragma unroll
        for (int mi = 0; mi < 4; ++mi)
            af[mi] = *reinterpret_cast<const bf16x8*>(
                &Alb[buf * 4096 + (wr * 64 + mi * 16 + lr) * 32 + kg * 8]);
        #pragma unroll
        for (int nf = 0; nf < 5; ++nf)
            bfr[nf] = *reinterpret_cast<const bf16x8*>(
                &Blb[buf * 6144 + (wc * 80 + nf * 16 + lr) * 32 + kg * 8]);
        #pragma unroll
        for (int mi = 0; mi < 4; ++mi)
            #pragma unroll
            for (int nf = 0; nf < 5; ++nf)
                acc[mi][nf] = __builtin_amdgcn_mfma_f32_16x16x32_bf16(af[mi], bfr[nf], acc[mi][nf], 0, 0, 0);

        __builtin_amdgcn_sched_barrier(0);
        __builtin_amdgcn_s_barrier();
        buf ^= 1;
    }

    // ---- LDS-staged coalesced epilogue, nontemporal ext-vector stores
    #pragma unroll
    for (int mi = 0; mi < 4; ++mi) {
        __syncthreads();
        #pragma unroll
        for (int nf = 0; nf < 5; ++nf) {
            const int ci = wc * 80 + nf * 16 + lr;
            const int col = n0 + ci;
            const float bb = (col < XD) ? bd2[col] : 0.f;
            #pragma unroll
            for (int j = 0; j < 4; ++j) {
                const int ri = wr * 16 + kg * 4 + j;
                const float v = acc[mi][nf][j] + bb;
                eb[ri * DEBLD + ci] = __builtin_amdgcn_rcpf(1.f + __expf(-v));
            }
        }
        __syncthreads();
        #pragma unroll
        for (int e = 0; e < 5; ++e) {
            const int q = e * 256 + tid;
            const int ri = q / 40;
            const int c4 = (q - ri * 40) * 4;
            const int col = n0 + c4;
            if (col < XD) {
                const int grow = m0 + (ri >> 4) * 64 + mi * 16 + (ri & 15);
                const f32x4 v = *reinterpret_cast<const f32x4*>(&eb[ri * DEBLD + c4]);
                __builtin_nontemporal_store(
                    v, reinterpret_cast<f32x4*>(&recon[(size_t)grow * XD + col]));
            }
        }
    }
    #undef DEC_STAGE
}

// ---------------------------------------------------------------------------
extern "C" void kernel_launch(void* const* d_in, const int* in_sizes, int n_in,
                              void* d_out, int out_size, void* d_ws, size_t ws_size,
                              hipStream_t stream)
{
    const float* x    = (const float*)d_in[0];
    const float* eps  = (const float*)d_in[1];
    const float* W1   = (const float*)d_in[2];
    const float* b1   = (const float*)d_in[3];
    const float* Wmu  = (const float*)d_in[4];
    const float* bmu  = (const float*)d_in[5];
    const float* Wstd = (const float*)d_in[6];
    const float* bstd = (const float*)d_in[7];
    const float* Wd1  = (const float*)d_in[8];
    const float* bd1  = (const float*)d_in[9];
    const float* Wd2  = (const float*)d_in[10];
    const float* bd2  = (const float*)d_in[11];

    float* out    = (float*)d_out;
    float* recon  = out;
    float* mu     = recon + (size_t)NSAMP * XD;
    float* logvar = mu + (size_t)BATCH * ZS;
    float* zout   = logvar + (size_t)NSAMP * ZD;

    char* wsb = (char*)d_ws;
    unsigned short* hd   = (unsigned short*)wsb;                            // 32 MiB
    unsigned short* x_bf = (unsigned short*)wsb;                            // 6.25 MiB
    unsigned short* h    = (unsigned short*)(wsb + (size_t)68 * 1048576 / 10);
    float*          ms   = (float*)(wsb + (size_t)11 * 1048576);
    unsigned short* w1t  = (unsigned short*)(wsb + (size_t)295 * 1048576 / 10);
    unsigned short* wmst = (unsigned short*)(wsb + (size_t)305 * 1048576 / 10);
    unsigned short* w2tp = (unsigned short*)(wsb + (size_t)32 * 1048576);   // 832x512 bf16 reachable

    prep_kernel<<<7104, 256, 0, stream>>>(W1, x, Wmu, Wstd, Wd2, w1t, x_bf, wmst, w2tp);

    // enc1: BM=64xBN=128 -> 256 blocks (full machine), XCD-swizzled
    enc1_mfma<<<256, 256, 0, stream>>>(x_bf, w1t, b1, h);
    // enc2: grid 32x9 = 288 blocks, XCD-swizzled (NT=9)
    enc_mfma<0><<<288, 256, 0, stream>>>(
        h, wmst, bmu, bstd, ZS, ms, NMS, HDIM, 9);

    samphd_kernel<<<BATCH / 2, 256, 0, stream>>>(ms, eps, Wd1, bd1, mu, zout, logvar, hd);

    // decoder: R13-exact, 1280 blocks
    decoder_mfma<<<1280, 256, 0, stream>>>(hd, w2tp, bd2, recon);
}